// Round 1
// baseline (222.632 us; speedup 1.0000x reference)
//
#include <hip/hip_runtime.h>

// Problem constants (from reference): x [B,C,H,W] fp32, guide [B,1,H,W] fp32.
// out[b,c,h,t] = max_{j<=t} x[b,c,h,j]*guide[b,0,h,j]  (cummax along W)
#define PB 8
#define PC 256
#define PH 128
#define PW 128

// One 32-lane half-wave per row of W=128: each lane owns a float4 (4 elems).
// Segmented shuffle scan (width=32) never crosses rows, so a 64-lane wave
// cleanly processes 2 rows and a 256-thread block processes 8 rows.
__global__ __launch_bounds__(256) void i5pool_cummax_kernel(
    const float* __restrict__ x,
    const float* __restrict__ guide,
    float* __restrict__ out)
{
    const int tid = blockIdx.x * blockDim.x + threadIdx.x;
    const int sub = tid & 31;        // quad index within the row (0..31)
    const int row = tid >> 5;        // global row id, 0 .. B*C*H-1 (=262144)

    // row = (b*PC + c)*PH + h
    const int h  = row & (PH - 1);
    const int bc = row >> 7;         // row / PH
    const int b  = bc >> 8;          // bc / PC

    const float4* xr = (const float4*)(x + (size_t)row * PW) + sub;
    const float4* gr = (const float4*)(guide + ((size_t)b * PH + h) * PW) + sub;

    float4 xv = *xr;
    float4 gv = *gr;

    // local inclusive max-scan of the 4 gated values
    float s0 = xv.x * gv.x;
    float s1 = fmaxf(s0, xv.y * gv.y);
    float s2 = fmaxf(s1, xv.z * gv.z);
    float s3 = fmaxf(s2, xv.w * gv.w);

    // inclusive scan of lane totals across the 32-lane segment
    float inc = s3;
    #pragma unroll
    for (int d = 1; d < 32; d <<= 1) {
        float t = __shfl_up(inc, d, 32);
        if (sub >= d) inc = fmaxf(inc, t);
    }
    // exclusive prefix = inclusive of lane-1
    float pre = __shfl_up(inc, 1, 32);
    if (sub > 0) {
        s0 = fmaxf(s0, pre);
        s1 = fmaxf(s1, pre);
        s2 = fmaxf(s2, pre);
        s3 = fmaxf(s3, pre);
    }

    float4 ov = make_float4(s0, s1, s2, s3);
    *((float4*)(out + (size_t)row * PW) + sub) = ov;
}

extern "C" void kernel_launch(void* const* d_in, const int* in_sizes, int n_in,
                              void* d_out, int out_size, void* d_ws, size_t ws_size,
                              hipStream_t stream) {
    const float* x     = (const float*)d_in[0];
    const float* guide = (const float*)d_in[1];
    float* out = (float*)d_out;

    // total rows = B*C*H = 262144; 32 lanes per row -> 8,388,608 threads
    const int total_threads = PB * PC * PH * (PW / 4);
    const int block = 256;
    const int grid = total_threads / block;  // 32768

    i5pool_cummax_kernel<<<grid, block, 0, stream>>>(x, guide, out);
}

// Round 3
// 220.872 us; speedup vs baseline: 1.0080x; 1.0080x over previous
//
#include <hip/hip_runtime.h>

// x [B,C,H,W] fp32, guide [B,1,H,W] fp32.
// out[b,c,h,t] = max_{j<=t} x[b,c,h,j]*guide[b,0,h,j]  (cummax along W)
#define PB 8
#define PC 256
#define PH 128
#define PW 128
#define TOTAL_ROWS (PB * PC * PH)      // 262144
#define HALF_ROWS  (TOTAL_ROWS / 2)    // 131072

// Native clang vector type — __builtin_nontemporal_* requires this
// (HIP's float4 is a class and is rejected).
typedef float vfloat4 __attribute__((ext_vector_type(4)));

// One 32-lane segment per row (lane owns a float4 = 4 elems). Each thread
// processes TWO independent rows (r, r+HALF_ROWS) for ILP / latency hiding.
// x loads and out stores are non-temporal (pure streaming, no reuse);
// guide stays on the cached path (reused by 256 channels).
__global__ __launch_bounds__(256) void i5pool_cummax_kernel(
    const float* __restrict__ x,
    const float* __restrict__ guide,
    float* __restrict__ out)
{
    const int tid = blockIdx.x * blockDim.x + threadIdx.x;
    const int sub = tid & 31;          // quad index within the row
    const int r0  = tid >> 5;          // first row, 0..HALF_ROWS-1
    const int r1  = r0 + HALF_ROWS;    // second row (independent work)

    // row = (b*PC + c)*PH + h  ->  guide row = (b*PH + h)
    const int h0 = r0 & (PH - 1);
    const int b0 = r0 >> 15;           // r0 / (PC*PH) = r0 / 32768
    const int h1 = r1 & (PH - 1);
    const int b1 = r1 >> 15;

    // Issue all loads up front (2 independent chains in flight per thread).
    const vfloat4* xp0 = (const vfloat4*)(x + (size_t)r0 * PW) + sub;
    const vfloat4* xp1 = (const vfloat4*)(x + (size_t)r1 * PW) + sub;
    const vfloat4* gp0 = (const vfloat4*)(guide + ((size_t)b0 * PH + h0) * PW) + sub;
    const vfloat4* gp1 = (const vfloat4*)(guide + ((size_t)b1 * PH + h1) * PW) + sub;

    vfloat4 xv0 = __builtin_nontemporal_load(xp0);
    vfloat4 xv1 = __builtin_nontemporal_load(xp1);
    vfloat4 gv0 = *gp0;
    vfloat4 gv1 = *gp1;

    // --- row 0 local scan ---
    float a0 = xv0.x * gv0.x;
    float a1 = fmaxf(a0, xv0.y * gv0.y);
    float a2 = fmaxf(a1, xv0.z * gv0.z);
    float a3 = fmaxf(a2, xv0.w * gv0.w);
    // --- row 1 local scan ---
    float c0 = xv1.x * gv1.x;
    float c1 = fmaxf(c0, xv1.y * gv1.y);
    float c2 = fmaxf(c1, xv1.z * gv1.z);
    float c3 = fmaxf(c2, xv1.w * gv1.w);

    // Interleaved 32-lane inclusive max-scans of lane totals (ILP).
    float incA = a3;
    float incC = c3;
    #pragma unroll
    for (int d = 1; d < 32; d <<= 1) {
        float tA = __shfl_up(incA, d, 32);
        float tC = __shfl_up(incC, d, 32);
        if (sub >= d) {
            incA = fmaxf(incA, tA);
            incC = fmaxf(incC, tC);
        }
    }
    float preA = __shfl_up(incA, 1, 32);
    float preC = __shfl_up(incC, 1, 32);
    if (sub > 0) {
        a0 = fmaxf(a0, preA); a1 = fmaxf(a1, preA);
        a2 = fmaxf(a2, preA); a3 = fmaxf(a3, preA);
        c0 = fmaxf(c0, preC); c1 = fmaxf(c1, preC);
        c2 = fmaxf(c2, preC); c3 = fmaxf(c3, preC);
    }

    vfloat4* op0 = (vfloat4*)(out + (size_t)r0 * PW) + sub;
    vfloat4* op1 = (vfloat4*)(out + (size_t)r1 * PW) + sub;
    vfloat4 ov0 = {a0, a1, a2, a3};
    vfloat4 ov1 = {c0, c1, c2, c3};
    __builtin_nontemporal_store(ov0, op0);
    __builtin_nontemporal_store(ov1, op1);
}

extern "C" void kernel_launch(void* const* d_in, const int* in_sizes, int n_in,
                              void* d_out, int out_size, void* d_ws, size_t ws_size,
                              hipStream_t stream) {
    const float* x     = (const float*)d_in[0];
    const float* guide = (const float*)d_in[1];
    float* out = (float*)d_out;

    // HALF_ROWS rows per "pass", 32 lanes per row -> 4,194,304 threads
    const int total_threads = HALF_ROWS * (PW / 4);
    const int block = 256;
    const int grid = total_threads / block;  // 16384

    i5pool_cummax_kernel<<<grid, block, 0, stream>>>(x, guide, out);
}